// Round 4
// baseline (322.169 us; speedup 1.0000x reference)
//
#include <hip/hip_runtime.h>

#define B_ 2048
#define T_ 200
#define D_ 64
#define NP 192  // per (b,t): [r_x(64) | u_x(64) | c_x(64)] fp16

constexpr int TCHUNK = 50;  // t-chunk per block in kernel 1 (4 chunks over T=200)

typedef _Float16 half_t;
typedef __attribute__((ext_vector_type(2))) _Float16 h2;
typedef __attribute__((ext_vector_type(8))) _Float16 h8;

#if defined(__has_builtin)
#if __has_builtin(__builtin_amdgcn_fdot2)
#define HAS_FDOT2 1
#endif
#endif

__device__ __forceinline__ float dot2f(h2 a, h2 b, float c) {
#ifdef HAS_FDOT2
  return __builtin_amdgcn_fdot2(a, b, c, false);
#else
  return fmaf((float)a[0], (float)b[0], fmaf((float)a[1], (float)b[1], c));
#endif
}

__device__ __forceinline__ h2 pick(h8 v, int i) {  // i compile-time after unroll
  h2 r;
  r[0] = v[2 * i];
  r[1] = v[2 * i + 1];
  return r;
}

__device__ __forceinline__ h2 mkh2(float a, float b) {
  h2 r;
  r[0] = (half_t)a;
  r[1] = (half_t)b;
  return r;
}

__device__ __forceinline__ float sigmoidf_(float x) {
  return 1.0f / (1.0f + __expf(-x));
}
__device__ __forceinline__ float tanhf_(float x) {
  x = fminf(fmaxf(x, -15.0f), 15.0f);
  float e = __expf(2.0f * x);
  return (e - 1.0f) / (e + 1.0f);
}

// ---------------- Kernel 1: x-part preactivations (batch-parallel GEMV) ----
// Xp[b,t,d]     = bg[d]    + sum_k x[k] * Wg[k][d]
// Xp[b,t,64+d]  = bg[64+d] + sum_k x[k] * Wg[k][64+d]
// Xp[b,t,128+d] = bc[d]    + sum_k x[k] * Wc[k][d]        (k = 0..63, fp16)
__global__ __launch_bounds__(64) void augru_xpre(
    const float* __restrict__ X, const int* __restrict__ SL,
    const float* __restrict__ Wg, const float* __restrict__ bg,
    const float* __restrict__ Wc, const float* __restrict__ bc,
    half_t* __restrict__ XP) {
  const int d = threadIdx.x;       // 0..63, one wave per block
  const int b = blockIdx.x >> 2;
  const int chunk = blockIdx.x & 3;
  const int L = SL[b];
  const int t0 = chunk * TCHUNK;
  if (t0 >= L) return;             // Xp past L is never read
  const int tend = (t0 + TCHUNK < L) ? t0 + TCHUNK : L;

  // x-part weight columns for output d: 96 VGPRs.
  h2 wxr[32], wxu[32], wxc[32];
#pragma unroll
  for (int k2 = 0; k2 < 32; ++k2) {
    wxr[k2] = mkh2(Wg[(2 * k2) * 128 + d], Wg[(2 * k2 + 1) * 128 + d]);
    wxu[k2] = mkh2(Wg[(2 * k2) * 128 + 64 + d], Wg[(2 * k2 + 1) * 128 + 64 + d]);
    wxc[k2] = mkh2(Wc[(2 * k2) * 64 + d], Wc[(2 * k2 + 1) * 64 + d]);
  }
  const float bgr = bg[d];
  const float bgu = bg[64 + d];
  const float bcd = bc[d];

  const float* __restrict__ xrow = X + (size_t)b * (T_ * D_);
  half_t* __restrict__ xp = XP + (size_t)b * (T_ * NP);

  // Software pipeline: nxt holds row t's floats; converted to cur at iter top.
  float4 nxt[16];
  {
    const float4* p = (const float4*)(xrow + t0 * D_);
#pragma unroll
    for (int j = 0; j < 16; ++j) nxt[j] = p[j];
  }

  for (int t = t0; t < tend; ++t) {
    h2 cur[32];
#pragma unroll
    for (int j = 0; j < 16; ++j) {
      cur[2 * j] = mkh2(nxt[j].x, nxt[j].y);
      cur[2 * j + 1] = mkh2(nxt[j].z, nxt[j].w);
    }
    // Issue next row's loads (clamped) under the dot compute.
    const int tn = (t + 1 < tend) ? t + 1 : t;
    {
      const float4* p = (const float4*)(xrow + tn * D_);
#pragma unroll
      for (int j = 0; j < 16; ++j) nxt[j] = p[j];
    }

    float r0 = bgr, r1 = 0.f, u0 = bgu, u1 = 0.f, c0 = bcd, c1 = 0.f;
#pragma unroll
    for (int q = 0; q < 8; ++q) {
      r0 = dot2f(cur[4 * q + 0], wxr[4 * q + 0], r0);
      r1 = dot2f(cur[4 * q + 1], wxr[4 * q + 1], r1);
      r0 = dot2f(cur[4 * q + 2], wxr[4 * q + 2], r0);
      r1 = dot2f(cur[4 * q + 3], wxr[4 * q + 3], r1);
      u0 = dot2f(cur[4 * q + 0], wxu[4 * q + 0], u0);
      u1 = dot2f(cur[4 * q + 1], wxu[4 * q + 1], u1);
      u0 = dot2f(cur[4 * q + 2], wxu[4 * q + 2], u0);
      u1 = dot2f(cur[4 * q + 3], wxu[4 * q + 3], u1);
      c0 = dot2f(cur[4 * q + 0], wxc[4 * q + 0], c0);
      c1 = dot2f(cur[4 * q + 1], wxc[4 * q + 1], c1);
      c0 = dot2f(cur[4 * q + 2], wxc[4 * q + 2], c0);
      c1 = dot2f(cur[4 * q + 3], wxc[4 * q + 3], c1);
    }
    half_t* o = xp + t * NP;
    o[d] = (half_t)(r0 + r1);
    o[64 + d] = (half_t)(u0 + u1);
    o[128 + d] = (half_t)(c0 + c1);
  }
}

// ---------------- Kernel 2: recurrence (h-part only) ----------------------
__global__ __launch_bounds__(64) void augru_rec(
    const half_t* __restrict__ XP, const int* __restrict__ SL,
    const float* __restrict__ ATT, const float* __restrict__ Wg,
    const float* __restrict__ Wc, float* __restrict__ OUT) {
  __shared__ __align__(16) half_t sH[64];
  __shared__ __align__(16) half_t sR[64];

  const int d = threadIdx.x;  // one wave per block, one batch row
  const int b = blockIdx.x;

  // h-part weight columns (rows k=64..127): 96 VGPRs.
  h2 wr[32], wu[32], wcc[32];
#pragma unroll
  for (int k2 = 0; k2 < 32; ++k2) {
    const int k = 64 + 2 * k2;
    wr[k2] = mkh2(Wg[k * 128 + d], Wg[(k + 1) * 128 + d]);
    wu[k2] = mkh2(Wg[k * 128 + 64 + d], Wg[(k + 1) * 128 + 64 + d]);
    wcc[k2] = mkh2(Wc[k * 64 + d], Wc[(k + 1) * 64 + d]);
  }

  const int L = SL[b];  // >= 1
  const half_t* __restrict__ xp = XP + (size_t)b * (T_ * NP);
  const float* __restrict__ arow = ATT + (size_t)b * T_;
  float* __restrict__ orow = OUT + (size_t)b * (T_ * D_);
  const h8* __restrict__ ph = (const h8*)sH;
  const h8* __restrict__ pr = (const h8*)sR;

  // 2-deep prefetch rotation for Xp triplet and att (covers HBM latency).
  half_t xr0 = xp[d], xu0 = xp[64 + d], xc0 = xp[128 + d];
  float a0 = arow[0];
  const int i1 = (1 < L) ? 1 : 0;
  half_t xr1 = xp[i1 * NP + d], xu1 = xp[i1 * NP + 64 + d],
         xc1 = xp[i1 * NP + 128 + d];
  float a1 = arow[i1];

  float h = 0.0f;

  for (int t = 0; t < L; ++t) {
    // Stage h for broadcast; same-wave DS ops are in-order (no hard drain).
    sH[d] = (half_t)h;
    asm volatile("" ::: "memory");

    // Prefetch t+2 (clamped).
    const int t2 = (t + 2 < L) ? t + 2 : (L - 1);
    const half_t tr = xp[t2 * NP + d];
    const half_t tu = xp[t2 * NP + 64 + d];
    const half_t tc = xp[t2 * NP + 128 + d];
    const float ta = arow[t2];

    // Read h blocks once; keep in regs for both r and u gates.
    h8 hb[8];
#pragma unroll
    for (int q = 0; q < 8; ++q) hb[q] = ph[q];

    // ---- r gate first (on the critical path to rh) ----
    float ar0 = (float)xr0, ar1 = 0.f;
#pragma unroll
    for (int q = 0; q < 8; ++q) {
      ar0 = dot2f(pick(hb[q], 0), wr[4 * q + 0], ar0);
      ar1 = dot2f(pick(hb[q], 1), wr[4 * q + 1], ar1);
      ar0 = dot2f(pick(hb[q], 2), wr[4 * q + 2], ar0);
      ar1 = dot2f(pick(hb[q], 3), wr[4 * q + 3], ar1);
    }
    const float r = sigmoidf_(ar0 + ar1);
    sR[d] = (half_t)(r * h);
    asm volatile("" ::: "memory");

    // ---- u gate from cached hb (fills the sR write->read latency) ----
    float au0 = (float)xu0, au1 = 0.f;
#pragma unroll
    for (int q = 0; q < 8; ++q) {
      au0 = dot2f(pick(hb[q], 0), wu[4 * q + 0], au0);
      au1 = dot2f(pick(hb[q], 1), wu[4 * q + 1], au1);
      au0 = dot2f(pick(hb[q], 2), wu[4 * q + 2], au0);
      au1 = dot2f(pick(hb[q], 3), wu[4 * q + 3], au1);
    }
    const float u = sigmoidf_(au0 + au1);

    // ---- candidate from rh broadcast ----
    float ac0 = (float)xc0, ac1 = 0.f;
#pragma unroll
    for (int q = 0; q < 8; ++q) {
      const h8 rb = pr[q];
      ac0 = dot2f(pick(rb, 0), wcc[4 * q + 0], ac0);
      ac1 = dot2f(pick(rb, 1), wcc[4 * q + 1], ac1);
      ac0 = dot2f(pick(rb, 2), wcc[4 * q + 2], ac0);
      ac1 = dot2f(pick(rb, 3), wcc[4 * q + 3], ac1);
    }
    const float c = tanhf_(ac0 + ac1);

    const float ua = a0 * u;
    h = fmaf(ua, c - h, h);  // (1-ua)*h + ua*c
    orow[t * D_ + d] = h;

    // Rotate prefetch registers (all static).
    xr0 = xr1; xu0 = xu1; xc0 = xc1; a0 = a1;
    xr1 = tr;  xu1 = tu;  xc1 = tc;  a1 = ta;
  }

  for (int t = L; t < T_; ++t) orow[t * D_ + d] = 0.0f;
}

// ---------------- Fallback (round-2 kernel, used if ws too small) ----------
constexpr int FWAVES = 4;
constexpr int FBLK = FWAVES * 64;
constexpr int FNBLK = B_ / FWAVES;

__global__ __launch_bounds__(FBLK, 2) void augru_dot2(
    const float* __restrict__ X, const int* __restrict__ SL,
    const float* __restrict__ ATT, const float* __restrict__ Wg,
    const float* __restrict__ bg, const float* __restrict__ Wc,
    const float* __restrict__ bc, float* __restrict__ OUT) {
  __shared__ __align__(16) half_t sV[FWAVES][192];

  const int tid = threadIdx.x;
  const int wave = tid >> 6;
  const int d = tid & 63;
  const int b = blockIdx.x * FWAVES + wave;

  h2 wr[64], wu[64], wc[64];
#pragma unroll
  for (int k2 = 0; k2 < 64; ++k2) {
    wr[k2] = mkh2(Wg[(2 * k2) * 128 + d], Wg[(2 * k2 + 1) * 128 + d]);
    wu[k2] = mkh2(Wg[(2 * k2) * 128 + 64 + d], Wg[(2 * k2 + 1) * 128 + 64 + d]);
    wc[k2] = mkh2(Wc[(2 * k2) * 64 + d], Wc[(2 * k2 + 1) * 64 + d]);
  }

  const float bgr = bg[d];
  const float bgu = bg[64 + d];
  const float bcd = bc[d];

  const int L = SL[b];
  const float* __restrict__ xrow = X + (size_t)b * (T_ * D_);
  const float* __restrict__ arow = ATT + (size_t)b * T_;
  float* __restrict__ orow = OUT + (size_t)b * (T_ * D_);

  half_t* __restrict__ vh = &sV[wave][0];
  const uint4* __restrict__ v4p = (const uint4*)vh;

  float h = 0.0f;
  float xn = xrow[d];
  float an = arow[0];

  for (int t = 0; t < L; ++t) {
    const float a_t = an;
    vh[d] = (half_t)xn;
    vh[64 + d] = (half_t)h;
    asm volatile("s_waitcnt lgkmcnt(0)" ::: "memory");

    const int tn = (t + 1 < L) ? t + 1 : t;
    const float xnn = xrow[tn * D_ + d];
    const float ann = arow[tn];

    float ar = bgr, au = bgu, ac = bcd;
#pragma unroll
    for (int q = 0; q < 16; ++q) {
      const uint4 blk = v4p[q];
      const h2 e0 = __builtin_bit_cast(h2, blk.x);
      const h2 e1 = __builtin_bit_cast(h2, blk.y);
      const h2 e2 = __builtin_bit_cast(h2, blk.z);
      const h2 e3 = __builtin_bit_cast(h2, blk.w);
      ar = dot2f(e0, wr[4 * q + 0], ar);
      ar = dot2f(e1, wr[4 * q + 1], ar);
      ar = dot2f(e2, wr[4 * q + 2], ar);
      ar = dot2f(e3, wr[4 * q + 3], ar);
      au = dot2f(e0, wu[4 * q + 0], au);
      au = dot2f(e1, wu[4 * q + 1], au);
      au = dot2f(e2, wu[4 * q + 2], au);
      au = dot2f(e3, wu[4 * q + 3], au);
      if (q < 8) {
        ac = dot2f(e0, wc[4 * q + 0], ac);
        ac = dot2f(e1, wc[4 * q + 1], ac);
        ac = dot2f(e2, wc[4 * q + 2], ac);
        ac = dot2f(e3, wc[4 * q + 3], ac);
      }
    }

    const float r = sigmoidf_(ar);
    const float u = sigmoidf_(au);

    vh[128 + d] = (half_t)(r * h);
    asm volatile("s_waitcnt lgkmcnt(0)" ::: "memory");

#pragma unroll
    for (int q = 0; q < 8; ++q) {
      const uint4 blk = v4p[16 + q];
      const h2 e0 = __builtin_bit_cast(h2, blk.x);
      const h2 e1 = __builtin_bit_cast(h2, blk.y);
      const h2 e2 = __builtin_bit_cast(h2, blk.z);
      const h2 e3 = __builtin_bit_cast(h2, blk.w);
      ac = dot2f(e0, wc[32 + 4 * q + 0], ac);
      ac = dot2f(e1, wc[32 + 4 * q + 1], ac);
      ac = dot2f(e2, wc[32 + 4 * q + 2], ac);
      ac = dot2f(e3, wc[32 + 4 * q + 3], ac);
    }

    const float c = tanhf_(ac);
    const float ua = a_t * u;
    h = fmaf(ua, c - h, h);
    orow[t * D_ + d] = h;

    xn = xnn;
    an = ann;
  }

  for (int t = L; t < T_; ++t) orow[t * D_ + d] = 0.0f;
}

extern "C" void kernel_launch(void* const* d_in, const int* in_sizes, int n_in,
                              void* d_out, int out_size, void* d_ws, size_t ws_size,
                              hipStream_t stream) {
  (void)in_sizes; (void)n_in; (void)out_size;
  const float* X  = (const float*)d_in[0];
  const int*   SL = (const int*)d_in[1];
  const float* A  = (const float*)d_in[2];
  const float* Wg = (const float*)d_in[3];
  const float* bg = (const float*)d_in[4];
  const float* Wc = (const float*)d_in[5];
  const float* bc = (const float*)d_in[6];
  float* O = (float*)d_out;

  const size_t need = (size_t)B_ * T_ * NP * sizeof(half_t);  // 157.3 MB
  if (ws_size >= need) {
    half_t* XP = (half_t*)d_ws;
    augru_xpre<<<B_ * 4, 64, 0, stream>>>(X, SL, Wg, bg, Wc, bc, XP);
    augru_rec<<<B_, 64, 0, stream>>>(XP, SL, A, Wg, Wc, O);
  } else {
    augru_dot2<<<FNBLK, FBLK, 0, stream>>>(X, SL, A, Wg, bg, Wc, bc, O);
  }
}

// Round 5
// 220.391 us; speedup vs baseline: 1.4618x; 1.4618x over previous
//
#include <hip/hip_runtime.h>

#define B_ 2048
#define T_ 200
#define D_ 64
#define NP 192  // per (b,t): [r_x(64) | u_x(64) | c_x(64)] fp16

constexpr int TCHUNK = 40;  // t-chunk per block in kernel 1 (5 chunks over T=200)

typedef _Float16 half_t;
typedef __attribute__((ext_vector_type(2))) _Float16 h2;
typedef __attribute__((ext_vector_type(8))) _Float16 h8;

#if defined(__has_builtin)
#if __has_builtin(__builtin_amdgcn_fdot2)
#define HAS_FDOT2 1
#endif
#endif

__device__ __forceinline__ float dot2f(h2 a, h2 b, float c) {
#ifdef HAS_FDOT2
  return __builtin_amdgcn_fdot2(a, b, c, false);
#else
  return fmaf((float)a[0], (float)b[0], fmaf((float)a[1], (float)b[1], c));
#endif
}

__device__ __forceinline__ h2 pick(h8 v, int i) {  // i compile-time after unroll
  h2 r;
  r[0] = v[2 * i];
  r[1] = v[2 * i + 1];
  return r;
}

__device__ __forceinline__ h2 mkh2(float a, float b) {
  h2 r;
  r[0] = (half_t)a;
  r[1] = (half_t)b;
  return r;
}

__device__ __forceinline__ float sigmoidf_(float x) {
  return 1.0f / (1.0f + __expf(-x));
}
__device__ __forceinline__ float tanhf_(float x) {
  x = fminf(fmaxf(x, -15.0f), 15.0f);
  float e = __expf(2.0f * x);
  return (e - 1.0f) / (e + 1.0f);
}

// ---------------- Kernel 1: x-part preactivations (batch-parallel GEMV) ----
// One wave per (b, t-chunk). Weights for column d in 96 VGPRs; x rows staged
// 8-at-a-time through LDS (coalesced float4 in, uniform b128 broadcast out).
__global__ __launch_bounds__(64, 2) void augru_xpre(
    const float* __restrict__ X, const int* __restrict__ SL,
    const float* __restrict__ Wg, const float* __restrict__ bg,
    const float* __restrict__ Wc, const float* __restrict__ bc,
    half_t* __restrict__ XP) {
  __shared__ __align__(16) half_t sX[8][64];

  const int d = threadIdx.x;        // 0..63
  const int chunk = blockIdx.x;     // 0..4
  const int b = blockIdx.y;         // 0..B-1
  const int L = SL[b];
  const int t0 = chunk * TCHUNK;
  if (t0 >= L) return;              // Xp past L is never read
  const int tend = (t0 + TCHUNK < L) ? t0 + TCHUNK : L;

  // x-part weight columns for output d: 96 VGPRs.
  h2 wxr[32], wxu[32], wxc[32];
#pragma unroll
  for (int k2 = 0; k2 < 32; ++k2) {
    wxr[k2] = mkh2(Wg[(2 * k2) * 128 + d], Wg[(2 * k2 + 1) * 128 + d]);
    wxu[k2] = mkh2(Wg[(2 * k2) * 128 + 64 + d], Wg[(2 * k2 + 1) * 128 + 64 + d]);
    wxc[k2] = mkh2(Wc[(2 * k2) * 64 + d], Wc[(2 * k2 + 1) * 64 + d]);
  }
  const float bgr = bg[d];
  const float bgu = bg[64 + d];
  const float bcd = bc[d];

  const float* __restrict__ xrow = X + (size_t)b * (T_ * D_);
  half_t* __restrict__ xp = XP + (size_t)b * (T_ * NP);
  const int rr = d >> 3;            // staging row this lane loads
  const int c8 = (d & 7) * 8;       // staging col offset (8 floats)
  const h8* __restrict__ px = (const h8*)&sX[0][0];

  for (int ts = t0; ts < tend; ts += 8) {
    // Stage rows ts..ts+7 (reads always in-bounds: ts+7 < t0+TCHUNK <= T).
    const float4 fa = *(const float4*)(xrow + (ts + rr) * D_ + c8);
    const float4 fb = *(const float4*)(xrow + (ts + rr) * D_ + c8 + 4);
    h8 hv;
    hv[0] = (half_t)fa.x; hv[1] = (half_t)fa.y;
    hv[2] = (half_t)fa.z; hv[3] = (half_t)fa.w;
    hv[4] = (half_t)fb.x; hv[5] = (half_t)fb.y;
    hv[6] = (half_t)fb.z; hv[7] = (half_t)fb.w;
    *(h8*)(&sX[rr][c8]) = hv;
    asm volatile("" ::: "memory");  // same-wave DS pipe is in-order

#pragma unroll
    for (int r = 0; r < 8; ++r) {
      const int t = ts + r;
      if (t >= tend) break;         // wave-uniform
      float r0 = bgr, r1 = 0.f, u0 = bgu, u1 = 0.f, c0 = bcd, c1 = 0.f;
#pragma unroll
      for (int q = 0; q < 8; ++q) {
        const h8 xb = px[r * 8 + q];  // uniform broadcast read
        r0 = dot2f(pick(xb, 0), wxr[4 * q + 0], r0);
        r1 = dot2f(pick(xb, 1), wxr[4 * q + 1], r1);
        r0 = dot2f(pick(xb, 2), wxr[4 * q + 2], r0);
        r1 = dot2f(pick(xb, 3), wxr[4 * q + 3], r1);
        u0 = dot2f(pick(xb, 0), wxu[4 * q + 0], u0);
        u1 = dot2f(pick(xb, 1), wxu[4 * q + 1], u1);
        u0 = dot2f(pick(xb, 2), wxu[4 * q + 2], u0);
        u1 = dot2f(pick(xb, 3), wxu[4 * q + 3], u1);
        c0 = dot2f(pick(xb, 0), wxc[4 * q + 0], c0);
        c1 = dot2f(pick(xb, 1), wxc[4 * q + 1], c1);
        c0 = dot2f(pick(xb, 2), wxc[4 * q + 2], c0);
        c1 = dot2f(pick(xb, 3), wxc[4 * q + 3], c1);
      }
      half_t* o = xp + (size_t)t * NP;
      o[d] = (half_t)(r0 + r1);
      o[64 + d] = (half_t)(u0 + u1);
      o[128 + d] = (half_t)(c0 + c1);
    }
    asm volatile("" ::: "memory");  // keep next staging write after these reads
  }
}

// ---------------- Kernel 2: recurrence (h-part only) ----------------------
__global__ __launch_bounds__(64, 2) void augru_rec(
    const half_t* __restrict__ XP, const int* __restrict__ SL,
    const float* __restrict__ ATT, const float* __restrict__ Wg,
    const float* __restrict__ Wc, float* __restrict__ OUT) {
  __shared__ __align__(16) half_t sH[64];
  __shared__ __align__(16) half_t sR[64];

  const int d = threadIdx.x;  // one wave per block, one batch row
  const int b = blockIdx.x;

  // h-part weight columns (rows k=64..127): 96 VGPRs.
  h2 wr[32], wu[32], wcc[32];
#pragma unroll
  for (int k2 = 0; k2 < 32; ++k2) {
    const int k = 64 + 2 * k2;
    wr[k2] = mkh2(Wg[k * 128 + d], Wg[(k + 1) * 128 + d]);
    wu[k2] = mkh2(Wg[k * 128 + 64 + d], Wg[(k + 1) * 128 + 64 + d]);
    wcc[k2] = mkh2(Wc[k * 64 + d], Wc[(k + 1) * 64 + d]);
  }

  const int L = SL[b];  // >= 1
  const half_t* __restrict__ xp = XP + (size_t)b * (T_ * NP);
  const float* __restrict__ arow = ATT + (size_t)b * T_;
  float* __restrict__ orow = OUT + (size_t)b * (T_ * D_);
  const h8* __restrict__ ph = (const h8*)sH;
  const h8* __restrict__ pr = (const h8*)sR;

  // h0 = 0: no LDS round trip needed for the first step.
  h8 hb[8];
#pragma unroll
  for (int q = 0; q < 8; ++q) {
#pragma unroll
    for (int i = 0; i < 8; ++i) hb[q][i] = (half_t)0.f;
  }

  // 2-deep prefetch rotation for Xp triplet and att.
  half_t xr0 = xp[d], xu0 = xp[64 + d], xc0 = xp[128 + d];
  float a0 = arow[0];
  const int i1 = (1 < L) ? 1 : 0;
  half_t xr1 = xp[i1 * NP + d], xu1 = xp[i1 * NP + 64 + d],
         xc1 = xp[i1 * NP + 128 + d];
  float a1 = arow[i1];

  float h = 0.0f;

  for (int t = 0; t < L; ++t) {
    // Prefetch t+2 (clamped; hidden under the dot chains).
    const int t2 = (t + 2 < L) ? t + 2 : (L - 1);
    const half_t tr = xp[t2 * NP + d];
    const half_t tu = xp[t2 * NP + 64 + d];
    const half_t tc = xp[t2 * NP + 128 + d];
    const float ta = arow[t2];

    // ---- r gate (critical path) + u gate, both from in-register hb ----
    float ar0 = (float)xr0, ar1 = 0.f, au0 = (float)xu0, au1 = 0.f;
#pragma unroll
    for (int q = 0; q < 8; ++q) {
      ar0 = dot2f(pick(hb[q], 0), wr[4 * q + 0], ar0);
      ar1 = dot2f(pick(hb[q], 1), wr[4 * q + 1], ar1);
      ar0 = dot2f(pick(hb[q], 2), wr[4 * q + 2], ar0);
      ar1 = dot2f(pick(hb[q], 3), wr[4 * q + 3], ar1);
      au0 = dot2f(pick(hb[q], 0), wu[4 * q + 0], au0);
      au1 = dot2f(pick(hb[q], 1), wu[4 * q + 1], au1);
      au0 = dot2f(pick(hb[q], 2), wu[4 * q + 2], au0);
      au1 = dot2f(pick(hb[q], 3), wu[4 * q + 3], au1);
    }
    const float r = sigmoidf_(ar0 + ar1);
    sR[d] = (half_t)(r * h);
    asm volatile("" ::: "memory");

    // u sigmoid + gate scale fill the sR write->read latency window.
    const float u = sigmoidf_(au0 + au1);
    const float ua = a0 * u;

    // ---- candidate from rh broadcast ----
    float ac0 = (float)xc0, ac1 = 0.f;
#pragma unroll
    for (int q = 0; q < 8; ++q) {
      const h8 rb = pr[q];
      ac0 = dot2f(pick(rb, 0), wcc[4 * q + 0], ac0);
      ac1 = dot2f(pick(rb, 1), wcc[4 * q + 1], ac1);
      ac0 = dot2f(pick(rb, 2), wcc[4 * q + 2], ac0);
      ac1 = dot2f(pick(rb, 3), wcc[4 * q + 3], ac1);
    }
    const float c = tanhf_(ac0 + ac1);

    h = fmaf(ua, c - h, h);  // (1-ua)*h + ua*c

    // Stage h for the NEXT step immediately; the ~120cy LDS latency hides
    // under the output store + prefetch rotation instead of the chain top.
    sH[d] = (half_t)h;
    asm volatile("" ::: "memory");
#pragma unroll
    for (int q = 0; q < 8; ++q) hb[q] = ph[q];

    orow[t * D_ + d] = h;

    xr0 = xr1; xu0 = xu1; xc0 = xc1; a0 = a1;
    xr1 = tr;  xu1 = tu;  xc1 = tc;  a1 = ta;
  }

  for (int t = L; t < T_; ++t) orow[t * D_ + d] = 0.0f;
}

// ---------------- Fallback (round-2 kernel, used if ws too small) ----------
constexpr int FWAVES = 4;
constexpr int FBLK = FWAVES * 64;
constexpr int FNBLK = B_ / FWAVES;

__global__ __launch_bounds__(FBLK, 2) void augru_dot2(
    const float* __restrict__ X, const int* __restrict__ SL,
    const float* __restrict__ ATT, const float* __restrict__ Wg,
    const float* __restrict__ bg, const float* __restrict__ Wc,
    const float* __restrict__ bc, float* __restrict__ OUT) {
  __shared__ __align__(16) half_t sV[FWAVES][192];

  const int tid = threadIdx.x;
  const int wave = tid >> 6;
  const int d = tid & 63;
  const int b = blockIdx.x * FWAVES + wave;

  h2 wr[64], wu[64], wc[64];
#pragma unroll
  for (int k2 = 0; k2 < 64; ++k2) {
    wr[k2] = mkh2(Wg[(2 * k2) * 128 + d], Wg[(2 * k2 + 1) * 128 + d]);
    wu[k2] = mkh2(Wg[(2 * k2) * 128 + 64 + d], Wg[(2 * k2 + 1) * 128 + 64 + d]);
    wc[k2] = mkh2(Wc[(2 * k2) * 64 + d], Wc[(2 * k2 + 1) * 64 + d]);
  }

  const float bgr = bg[d];
  const float bgu = bg[64 + d];
  const float bcd = bc[d];

  const int L = SL[b];
  const float* __restrict__ xrow = X + (size_t)b * (T_ * D_);
  const float* __restrict__ arow = ATT + (size_t)b * T_;
  float* __restrict__ orow = OUT + (size_t)b * (T_ * D_);

  half_t* __restrict__ vh = &sV[wave][0];
  const uint4* __restrict__ v4p = (const uint4*)vh;

  float h = 0.0f;
  float xn = xrow[d];
  float an = arow[0];

  for (int t = 0; t < L; ++t) {
    const float a_t = an;
    vh[d] = (half_t)xn;
    vh[64 + d] = (half_t)h;
    asm volatile("s_waitcnt lgkmcnt(0)" ::: "memory");

    const int tn = (t + 1 < L) ? t + 1 : t;
    const float xnn = xrow[tn * D_ + d];
    const float ann = arow[tn];

    float ar = bgr, au = bgu, ac = bcd;
#pragma unroll
    for (int q = 0; q < 16; ++q) {
      const uint4 blk = v4p[q];
      const h2 e0 = __builtin_bit_cast(h2, blk.x);
      const h2 e1 = __builtin_bit_cast(h2, blk.y);
      const h2 e2 = __builtin_bit_cast(h2, blk.z);
      const h2 e3 = __builtin_bit_cast(h2, blk.w);
      ar = dot2f(e0, wr[4 * q + 0], ar);
      ar = dot2f(e1, wr[4 * q + 1], ar);
      ar = dot2f(e2, wr[4 * q + 2], ar);
      ar = dot2f(e3, wr[4 * q + 3], ar);
      au = dot2f(e0, wu[4 * q + 0], au);
      au = dot2f(e1, wu[4 * q + 1], au);
      au = dot2f(e2, wu[4 * q + 2], au);
      au = dot2f(e3, wu[4 * q + 3], au);
      if (q < 8) {
        ac = dot2f(e0, wc[4 * q + 0], ac);
        ac = dot2f(e1, wc[4 * q + 1], ac);
        ac = dot2f(e2, wc[4 * q + 2], ac);
        ac = dot2f(e3, wc[4 * q + 3], ac);
      }
    }

    const float r = sigmoidf_(ar);
    const float u = sigmoidf_(au);

    vh[128 + d] = (half_t)(r * h);
    asm volatile("s_waitcnt lgkmcnt(0)" ::: "memory");

#pragma unroll
    for (int q = 0; q < 8; ++q) {
      const uint4 blk = v4p[16 + q];
      const h2 e0 = __builtin_bit_cast(h2, blk.x);
      const h2 e1 = __builtin_bit_cast(h2, blk.y);
      const h2 e2 = __builtin_bit_cast(h2, blk.z);
      const h2 e3 = __builtin_bit_cast(h2, blk.w);
      ac = dot2f(e0, wc[32 + 4 * q + 0], ac);
      ac = dot2f(e1, wc[32 + 4 * q + 1], ac);
      ac = dot2f(e2, wc[32 + 4 * q + 2], ac);
      ac = dot2f(e3, wc[32 + 4 * q + 3], ac);
    }

    const float c = tanhf_(ac);
    const float ua = a_t * u;
    h = fmaf(ua, c - h, h);
    orow[t * D_ + d] = h;

    xn = xnn;
    an = ann;
  }

  for (int t = L; t < T_; ++t) orow[t * D_ + d] = 0.0f;
}

extern "C" void kernel_launch(void* const* d_in, const int* in_sizes, int n_in,
                              void* d_out, int out_size, void* d_ws, size_t ws_size,
                              hipStream_t stream) {
  (void)in_sizes; (void)n_in; (void)out_size;
  const float* X  = (const float*)d_in[0];
  const int*   SL = (const int*)d_in[1];
  const float* A  = (const float*)d_in[2];
  const float* Wg = (const float*)d_in[3];
  const float* bg = (const float*)d_in[4];
  const float* Wc = (const float*)d_in[5];
  const float* bc = (const float*)d_in[6];
  float* O = (float*)d_out;

  const size_t need = (size_t)B_ * T_ * NP * sizeof(half_t);  // 157.3 MB
  if (ws_size >= need) {
    half_t* XP = (half_t*)d_ws;
    dim3 grid(T_ / TCHUNK, B_);
    augru_xpre<<<grid, 64, 0, stream>>>(X, SL, Wg, bg, Wc, bc, XP);
    augru_rec<<<B_, 64, 0, stream>>>(XP, SL, A, Wg, Wc, O);
  } else {
    augru_dot2<<<FNBLK, FBLK, 0, stream>>>(X, SL, A, Wg, bg, Wc, bc, O);
  }
}

// Round 6
// 219.044 us; speedup vs baseline: 1.4708x; 1.0061x over previous
//
#include <hip/hip_runtime.h>

#define B_ 2048
#define T_ 200
#define D_ 64
#define NP 192  // per (b,t): [r_x(64) | u_x(64) | c_x(64)] fp16

constexpr int TCHUNK = 40;  // t-chunk per block in kernel 1 (5 chunks over T=200)

typedef _Float16 half_t;
typedef __attribute__((ext_vector_type(2))) _Float16 h2;
typedef __attribute__((ext_vector_type(8))) _Float16 h8;

#if defined(__has_builtin)
#if __has_builtin(__builtin_amdgcn_fdot2)
#define HAS_FDOT2 1
#endif
#endif

__device__ __forceinline__ float dot2f(h2 a, h2 b, float c) {
#ifdef HAS_FDOT2
  return __builtin_amdgcn_fdot2(a, b, c, false);
#else
  return fmaf((float)a[0], (float)b[0], fmaf((float)a[1], (float)b[1], c));
#endif
}

__device__ __forceinline__ h2 pick(h8 v, int i) {  // i compile-time after unroll
  h2 r;
  r[0] = v[2 * i];
  r[1] = v[2 * i + 1];
  return r;
}

__device__ __forceinline__ h2 mkh2(float a, float b) {
  h2 r;
  r[0] = (half_t)a;
  r[1] = (half_t)b;
  return r;
}

__device__ __forceinline__ float sigmoidf_(float x) {
  return 1.0f / (1.0f + __expf(-x));
}
__device__ __forceinline__ float tanhf_(float x) {
  x = fminf(fmaxf(x, -15.0f), 15.0f);
  float e = __expf(2.0f * x);
  return (e - 1.0f) / (e + 1.0f);
}

// ---------------- Kernel 1: x-part preactivations (batch-parallel GEMV) ----
// One wave per (b, t-chunk). Weights for column d in 96 VGPRs; x rows staged
// 8-at-a-time through LDS (coalesced float4 in, uniform b128 broadcast out).
// amdgpu_waves_per_eu(2,2): cap target occupancy at 2 waves/EU -> 256-VGPR
// budget, so the scheduler keeps the weight columns register-resident
// instead of remat-sinking the loads into the loop (rounds 2-5 failure).
__global__ __launch_bounds__(64)
__attribute__((amdgpu_waves_per_eu(2, 2))) void augru_xpre(
    const float* __restrict__ X, const int* __restrict__ SL,
    const float* __restrict__ Wg, const float* __restrict__ bg,
    const float* __restrict__ Wc, const float* __restrict__ bc,
    half_t* __restrict__ XP) {
  __shared__ __align__(16) half_t sX[8][64];

  const int d = threadIdx.x;        // 0..63
  const int chunk = blockIdx.x;     // 0..4
  const int b = blockIdx.y;         // 0..B-1
  const int L = SL[b];
  const int t0 = chunk * TCHUNK;
  if (t0 >= L) return;              // Xp past L is never read
  const int tend = (t0 + TCHUNK < L) ? t0 + TCHUNK : L;

  // x-part weight columns for output d: 96 VGPRs.
  h2 wxr[32], wxu[32], wxc[32];
#pragma unroll
  for (int k2 = 0; k2 < 32; ++k2) {
    wxr[k2] = mkh2(Wg[(2 * k2) * 128 + d], Wg[(2 * k2 + 1) * 128 + d]);
    wxu[k2] = mkh2(Wg[(2 * k2) * 128 + 64 + d], Wg[(2 * k2 + 1) * 128 + 64 + d]);
    wxc[k2] = mkh2(Wc[(2 * k2) * 64 + d], Wc[(2 * k2 + 1) * 64 + d]);
  }
  const float bgr = bg[d];
  const float bgu = bg[64 + d];
  const float bcd = bc[d];

  const float* __restrict__ xrow = X + (size_t)b * (T_ * D_);
  half_t* __restrict__ xp = XP + (size_t)b * (T_ * NP);
  const int rr = d >> 3;            // staging row this lane loads
  const int c8 = (d & 7) * 8;       // staging col offset (8 floats)
  const h8* __restrict__ px = (const h8*)&sX[0][0];

  for (int ts = t0; ts < tend; ts += 8) {
    // Stage rows ts..ts+7 (reads always in-bounds: ts+7 < t0+TCHUNK <= T).
    const float4 fa = *(const float4*)(xrow + (ts + rr) * D_ + c8);
    const float4 fb = *(const float4*)(xrow + (ts + rr) * D_ + c8 + 4);
    h8 hv;
    hv[0] = (half_t)fa.x; hv[1] = (half_t)fa.y;
    hv[2] = (half_t)fa.z; hv[3] = (half_t)fa.w;
    hv[4] = (half_t)fb.x; hv[5] = (half_t)fb.y;
    hv[6] = (half_t)fb.z; hv[7] = (half_t)fb.w;
    *(h8*)(&sX[rr][c8]) = hv;
    asm volatile("" ::: "memory");  // same-wave DS pipe is in-order

#pragma unroll
    for (int r = 0; r < 8; ++r) {
      const int t = ts + r;
      if (t >= tend) break;         // wave-uniform
      float r0 = bgr, r1 = 0.f, u0 = bgu, u1 = 0.f, c0 = bcd, c1 = 0.f;
#pragma unroll
      for (int q = 0; q < 8; ++q) {
        const h8 xb = px[r * 8 + q];  // uniform broadcast read
        r0 = dot2f(pick(xb, 0), wxr[4 * q + 0], r0);
        r1 = dot2f(pick(xb, 1), wxr[4 * q + 1], r1);
        r0 = dot2f(pick(xb, 2), wxr[4 * q + 2], r0);
        r1 = dot2f(pick(xb, 3), wxr[4 * q + 3], r1);
        u0 = dot2f(pick(xb, 0), wxu[4 * q + 0], u0);
        u1 = dot2f(pick(xb, 1), wxu[4 * q + 1], u1);
        u0 = dot2f(pick(xb, 2), wxu[4 * q + 2], u0);
        u1 = dot2f(pick(xb, 3), wxu[4 * q + 3], u1);
        c0 = dot2f(pick(xb, 0), wxc[4 * q + 0], c0);
        c1 = dot2f(pick(xb, 1), wxc[4 * q + 1], c1);
        c0 = dot2f(pick(xb, 2), wxc[4 * q + 2], c0);
        c1 = dot2f(pick(xb, 3), wxc[4 * q + 3], c1);
      }
      half_t* o = xp + (size_t)t * NP;
      o[d] = (half_t)(r0 + r1);
      o[64 + d] = (half_t)(u0 + u1);
      o[128 + d] = (half_t)(c0 + c1);
    }
    asm volatile("" ::: "memory");  // keep next staging write after these reads
  }
}

// ---------------- Kernel 2: recurrence (h-part only) ----------------------
__global__ __launch_bounds__(64)
__attribute__((amdgpu_waves_per_eu(2, 2))) void augru_rec(
    const half_t* __restrict__ XP, const int* __restrict__ SL,
    const float* __restrict__ ATT, const float* __restrict__ Wg,
    const float* __restrict__ Wc, float* __restrict__ OUT) {
  __shared__ __align__(16) half_t sH[64];
  __shared__ __align__(16) half_t sR[64];

  const int d = threadIdx.x;  // one wave per block, one batch row
  const int b = blockIdx.x;

  // h-part weight columns (rows k=64..127): 96 VGPRs.
  h2 wr[32], wu[32], wcc[32];
#pragma unroll
  for (int k2 = 0; k2 < 32; ++k2) {
    const int k = 64 + 2 * k2;
    wr[k2] = mkh2(Wg[k * 128 + d], Wg[(k + 1) * 128 + d]);
    wu[k2] = mkh2(Wg[k * 128 + 64 + d], Wg[(k + 1) * 128 + 64 + d]);
    wcc[k2] = mkh2(Wc[k * 64 + d], Wc[(k + 1) * 64 + d]);
  }

  const int L = SL[b];  // >= 1
  const half_t* __restrict__ xp = XP + (size_t)b * (T_ * NP);
  const float* __restrict__ arow = ATT + (size_t)b * T_;
  float* __restrict__ orow = OUT + (size_t)b * (T_ * D_);
  const h8* __restrict__ ph = (const h8*)sH;
  const h8* __restrict__ pr = (const h8*)sR;

  // h0 = 0: no LDS round trip needed for the first step.
  h8 hb[8];
#pragma unroll
  for (int q = 0; q < 8; ++q) {
#pragma unroll
    for (int i = 0; i < 8; ++i) hb[q][i] = (half_t)0.f;
  }

  // 2-deep prefetch rotation for Xp triplet and att.
  half_t xr0 = xp[d], xu0 = xp[64 + d], xc0 = xp[128 + d];
  float a0 = arow[0];
  const int i1 = (1 < L) ? 1 : 0;
  half_t xr1 = xp[i1 * NP + d], xu1 = xp[i1 * NP + 64 + d],
         xc1 = xp[i1 * NP + 128 + d];
  float a1 = arow[i1];

  float h = 0.0f;

  for (int t = 0; t < L; ++t) {
    // Prefetch t+2 (clamped; hidden under the dot chains).
    const int t2 = (t + 2 < L) ? t + 2 : (L - 1);
    const half_t tr = xp[t2 * NP + d];
    const half_t tu = xp[t2 * NP + 64 + d];
    const half_t tc = xp[t2 * NP + 128 + d];
    const float ta = arow[t2];

    // ---- r gate (critical path) + u gate, both from in-register hb ----
    float ar0 = (float)xr0, ar1 = 0.f, au0 = (float)xu0, au1 = 0.f;
#pragma unroll
    for (int q = 0; q < 8; ++q) {
      ar0 = dot2f(pick(hb[q], 0), wr[4 * q + 0], ar0);
      ar1 = dot2f(pick(hb[q], 1), wr[4 * q + 1], ar1);
      ar0 = dot2f(pick(hb[q], 2), wr[4 * q + 2], ar0);
      ar1 = dot2f(pick(hb[q], 3), wr[4 * q + 3], ar1);
      au0 = dot2f(pick(hb[q], 0), wu[4 * q + 0], au0);
      au1 = dot2f(pick(hb[q], 1), wu[4 * q + 1], au1);
      au0 = dot2f(pick(hb[q], 2), wu[4 * q + 2], au0);
      au1 = dot2f(pick(hb[q], 3), wu[4 * q + 3], au1);
    }
    const float r = sigmoidf_(ar0 + ar1);
    sR[d] = (half_t)(r * h);
    asm volatile("" ::: "memory");

    // u sigmoid + gate scale fill the sR write->read latency window.
    const float u = sigmoidf_(au0 + au1);
    const float ua = a0 * u;

    // ---- candidate from rh broadcast ----
    float ac0 = (float)xc0, ac1 = 0.f;
#pragma unroll
    for (int q = 0; q < 8; ++q) {
      const h8 rb = pr[q];
      ac0 = dot2f(pick(rb, 0), wcc[4 * q + 0], ac0);
      ac1 = dot2f(pick(rb, 1), wcc[4 * q + 1], ac1);
      ac0 = dot2f(pick(rb, 2), wcc[4 * q + 2], ac0);
      ac1 = dot2f(pick(rb, 3), wcc[4 * q + 3], ac1);
    }
    const float c = tanhf_(ac0 + ac1);

    h = fmaf(ua, c - h, h);  // (1-ua)*h + ua*c

    // Stage h for the NEXT step immediately; the ~120cy LDS latency hides
    // under the output store + prefetch rotation instead of the chain top.
    sH[d] = (half_t)h;
    asm volatile("" ::: "memory");
#pragma unroll
    for (int q = 0; q < 8; ++q) hb[q] = ph[q];

    orow[t * D_ + d] = h;

    xr0 = xr1; xu0 = xu1; xc0 = xc1; a0 = a1;
    xr1 = tr;  xu1 = tu;  xc1 = tc;  a1 = ta;
  }

  for (int t = L; t < T_; ++t) orow[t * D_ + d] = 0.0f;
}

// ---------------- Fallback (round-2 kernel, used if ws too small) ----------
constexpr int FWAVES = 4;
constexpr int FBLK = FWAVES * 64;
constexpr int FNBLK = B_ / FWAVES;

__global__ __launch_bounds__(FBLK)
__attribute__((amdgpu_waves_per_eu(2, 2))) void augru_dot2(
    const float* __restrict__ X, const int* __restrict__ SL,
    const float* __restrict__ ATT, const float* __restrict__ Wg,
    const float* __restrict__ bg, const float* __restrict__ Wc,
    const float* __restrict__ bc, float* __restrict__ OUT) {
  __shared__ __align__(16) half_t sV[FWAVES][192];

  const int tid = threadIdx.x;
  const int wave = tid >> 6;
  const int d = tid & 63;
  const int b = blockIdx.x * FWAVES + wave;

  h2 wr[64], wu[64], wc[64];
#pragma unroll
  for (int k2 = 0; k2 < 64; ++k2) {
    wr[k2] = mkh2(Wg[(2 * k2) * 128 + d], Wg[(2 * k2 + 1) * 128 + d]);
    wu[k2] = mkh2(Wg[(2 * k2) * 128 + 64 + d], Wg[(2 * k2 + 1) * 128 + 64 + d]);
    wc[k2] = mkh2(Wc[(2 * k2) * 64 + d], Wc[(2 * k2 + 1) * 64 + d]);
  }

  const float bgr = bg[d];
  const float bgu = bg[64 + d];
  const float bcd = bc[d];

  const int L = SL[b];
  const float* __restrict__ xrow = X + (size_t)b * (T_ * D_);
  const float* __restrict__ arow = ATT + (size_t)b * T_;
  float* __restrict__ orow = OUT + (size_t)b * (T_ * D_);

  half_t* __restrict__ vh = &sV[wave][0];
  const uint4* __restrict__ v4p = (const uint4*)vh;

  float h = 0.0f;
  float xn = xrow[d];
  float an = arow[0];

  for (int t = 0; t < L; ++t) {
    const float a_t = an;
    vh[d] = (half_t)xn;
    vh[64 + d] = (half_t)h;
    asm volatile("s_waitcnt lgkmcnt(0)" ::: "memory");

    const int tn = (t + 1 < L) ? t + 1 : t;
    const float xnn = xrow[tn * D_ + d];
    const float ann = arow[tn];

    float ar = bgr, au = bgu, ac = bcd;
#pragma unroll
    for (int q = 0; q < 16; ++q) {
      const uint4 blk = v4p[q];
      const h2 e0 = __builtin_bit_cast(h2, blk.x);
      const h2 e1 = __builtin_bit_cast(h2, blk.y);
      const h2 e2 = __builtin_bit_cast(h2, blk.z);
      const h2 e3 = __builtin_bit_cast(h2, blk.w);
      ar = dot2f(e0, wr[4 * q + 0], ar);
      ar = dot2f(e1, wr[4 * q + 1], ar);
      ar = dot2f(e2, wr[4 * q + 2], ar);
      ar = dot2f(e3, wr[4 * q + 3], ar);
      au = dot2f(e0, wu[4 * q + 0], au);
      au = dot2f(e1, wu[4 * q + 1], au);
      au = dot2f(e2, wu[4 * q + 2], au);
      au = dot2f(e3, wu[4 * q + 3], au);
      if (q < 8) {
        ac = dot2f(e0, wc[4 * q + 0], ac);
        ac = dot2f(e1, wc[4 * q + 1], ac);
        ac = dot2f(e2, wc[4 * q + 2], ac);
        ac = dot2f(e3, wc[4 * q + 3], ac);
      }
    }

    const float r = sigmoidf_(ar);
    const float u = sigmoidf_(au);

    vh[128 + d] = (half_t)(r * h);
    asm volatile("s_waitcnt lgkmcnt(0)" ::: "memory");

#pragma unroll
    for (int q = 0; q < 8; ++q) {
      const uint4 blk = v4p[16 + q];
      const h2 e0 = __builtin_bit_cast(h2, blk.x);
      const h2 e1 = __builtin_bit_cast(h2, blk.y);
      const h2 e2 = __builtin_bit_cast(h2, blk.z);
      const h2 e3 = __builtin_bit_cast(h2, blk.w);
      ac = dot2f(e0, wc[32 + 4 * q + 0], ac);
      ac = dot2f(e1, wc[32 + 4 * q + 1], ac);
      ac = dot2f(e2, wc[32 + 4 * q + 2], ac);
      ac = dot2f(e3, wc[32 + 4 * q + 3], ac);
    }

    const float c = tanhf_(ac);
    const float ua = a_t * u;
    h = fmaf(ua, c - h, h);
    orow[t * D_ + d] = h;

    xn = xnn;
    an = ann;
  }

  for (int t = L; t < T_; ++t) orow[t * D_ + d] = 0.0f;
}

extern "C" void kernel_launch(void* const* d_in, const int* in_sizes, int n_in,
                              void* d_out, int out_size, void* d_ws, size_t ws_size,
                              hipStream_t stream) {
  (void)in_sizes; (void)n_in; (void)out_size;
  const float* X  = (const float*)d_in[0];
  const int*   SL = (const int*)d_in[1];
  const float* A  = (const float*)d_in[2];
  const float* Wg = (const float*)d_in[3];
  const float* bg = (const float*)d_in[4];
  const float* Wc = (const float*)d_in[5];
  const float* bc = (const float*)d_in[6];
  float* O = (float*)d_out;

  const size_t need = (size_t)B_ * T_ * NP * sizeof(half_t);  // 157.3 MB
  if (ws_size >= need) {
    half_t* XP = (half_t*)d_ws;
    dim3 grid(T_ / TCHUNK, B_);
    augru_xpre<<<grid, 64, 0, stream>>>(X, SL, Wg, bg, Wc, bc, XP);
    augru_rec<<<B_, 64, 0, stream>>>(XP, SL, A, Wg, Wc, O);
  } else {
    augru_dot2<<<FNBLK, FBLK, 0, stream>>>(X, SL, A, Wg, bg, Wc, bc, O);
  }
}